// Round 8
// baseline (622.067 us; speedup 1.0000x reference)
//
#include <hip/hip_runtime.h>
#include <hip/hip_cooperative_groups.h>

namespace cg = cooperative_groups;

#define HID 64
#define IN_CH 128

#define BSHIFT 9          // 512 nodes per bucket
#define NBUK_MAX 256      // supports N up to 131072 (src packed in 17 bits)
#define CAP 16384         // fixed edge capacity per bucket region (~3x headroom)
#define EPB 2048          // edges per partition block

// LDS scratch: max over phases = partition (3*256*4 + 2048*8 = 19456 B)
#define SMBYTES 19456

typedef __attribute__((ext_vector_type(8))) short bf16x8;
typedef __attribute__((ext_vector_type(4))) float f32x4;

// ---------- bf16 helpers (RNE) ----------
__device__ __forceinline__ float bf2f(unsigned short u) {
    return __uint_as_float((unsigned)u << 16);
}
__device__ __forceinline__ unsigned short f2bf(float f) {
    unsigned u = __float_as_uint(f);
    unsigned r = u + 0x7FFFu + ((u >> 16) & 1u);
    return (unsigned short)(r >> 16);
}

// swizzled LDS byte offset for a [rows][64] bf16 tile (row stride 128B).
__device__ __forceinline__ int lds_swz(int row, int byte_col) {
    return row * 128 + (byte_col ^ ((row & 7) << 4));
}

// ================= phase bodies (shared by mega + fallback) =================

// ---- P0 chunk c in [0,5): zero gcursor / weight transposes ----
__device__ __forceinline__ void prep_chunk(
    int c, int* gcursor, const float* pw, const float* w0f,
    const float* w1f, const float* w2f, unsigned short* pwT,
    unsigned short* wT) {
    const int t = threadIdx.x;
    if (c == 0) {
        if (t < NBUK_MAX) gcursor[t] = 0;
    } else if (c == 1) {
        for (int i = t; i < IN_CH * HID; i += 256) {
            const int k = i >> 6, n = i & 63;
            pwT[n * IN_CH + k] = f2bf(pw[i]);
        }
    } else {
        const float* w = (c == 2) ? w0f : (c == 3) ? w1f : w2f;
        unsigned short* o = wT + (size_t)(c - 2) * HID * HID;
        for (int i = t; i < HID * HID; i += 256) {
            const int k = i >> 6, n = i & 63;
            o[n * HID + k] = f2bf(w[i]);
        }
    }
}

// ---- partition chunk: counting-sort EPB edges into fixed bucket regions ----
__device__ __forceinline__ void partition_chunk(
    char* smraw, int c, const int* src, const int* dst,
    int* gcursor, int* binned, int E) {
    int* lh = (int*)smraw;
    int* loff = lh + NBUK_MAX;
    int* gbase = loff + NBUK_MAX;
    int2* stage = (int2*)(gbase + NBUK_MAX);
    const int t = threadIdx.x;
    const int base = c * EPB;
    const int count = min(EPB, E - base);

    for (int i = t; i < NBUK_MAX; i += 256) lh[i] = 0;
    __syncthreads();

    constexpr int EPT = EPB / 256;
    int myS[EPT], myD[EPT], myR[EPT];
#pragma unroll
    for (int j = 0; j < EPT; ++j) {
        const int e = base + j * 256 + t;
        if (e < E) {
            myS[j] = src[e];
            myD[j] = dst[e];
            myR[j] = atomicAdd(&lh[myD[j] >> BSHIFT], 1);
        }
    }
    __syncthreads();

    const int v = lh[t];
    loff[t] = v;
    __syncthreads();
    for (int d = 1; d < 256; d <<= 1) {
        int xx = loff[t];
        int yy = (t >= d) ? loff[t - d] : 0;
        __syncthreads();
        loff[t] = xx + yy;
        __syncthreads();
    }
    const int excl = loff[t] - v;
    __syncthreads();
    loff[t] = excl;
    if (v > 0) gbase[t] = t * CAP + atomicAdd(&gcursor[t], v);
    __syncthreads();

#pragma unroll
    for (int j = 0; j < EPT; ++j) {
        const int e = base + j * 256 + t;
        if (e < E) {
            const int bb = myD[j] >> BSHIFT;
            stage[loff[bb] + myR[j]] = make_int2(myS[j], myD[j]);
        }
    }
    __syncthreads();

    for (int i = t; i < count; i += 256) {
        const int2 ed = stage[i];
        const int bb = ed.y >> BSHIFT;
        const int pos = gbase[bb] + (i - loff[bb]);
        if (pos - bb * CAP < CAP) {  // overflow guard
            binned[pos] = ed.x | ((ed.y & ((1 << BSHIFT) - 1)) << 17);
        }
    }
}

// ---- proj chunk: res[64 rows] = bf16(x@pwT + pb), 4 waves x 16 rows ----
__device__ __forceinline__ void proj_chunk(
    int c, const float* A, const unsigned short* pwT, const float* bias,
    unsigned short* res, int N) {
    const int t = threadIdx.x;
    const int wave = t >> 6;
    const int lane = t & 63;
    const int quad = lane >> 4;
    const int m = lane & 15;
    const int rowbase = c * 64 + wave * 16;
    const int row = rowbase + m;

    f32x4 acc[4];
#pragma unroll
    for (int nt = 0; nt < 4; nt++) acc[nt] = (f32x4){0.f, 0.f, 0.f, 0.f};

#pragma unroll
    for (int ks = 0; ks < IN_CH; ks += 32) {
        union { bf16x8 v; unsigned short u[8]; } af;
        if (row < N) {
            const float4 a0 = *(const float4*)&A[(size_t)row * IN_CH + ks + quad * 8];
            const float4 a1 = *(const float4*)&A[(size_t)row * IN_CH + ks + quad * 8 + 4];
            af.u[0] = f2bf(a0.x); af.u[1] = f2bf(a0.y);
            af.u[2] = f2bf(a0.z); af.u[3] = f2bf(a0.w);
            af.u[4] = f2bf(a1.x); af.u[5] = f2bf(a1.y);
            af.u[6] = f2bf(a1.z); af.u[7] = f2bf(a1.w);
        } else {
#pragma unroll
            for (int j = 0; j < 8; j++) af.u[j] = 0;
        }
#pragma unroll
        for (int nt = 0; nt < 4; nt++) {
            const bf16x8 bfrag = *(const bf16x8*)&pwT[(nt * 16 + m) * IN_CH + ks + quad * 8];
            acc[nt] = __builtin_amdgcn_mfma_f32_16x16x32_bf16(af.v, bfrag, acc[nt], 0, 0, 0);
        }
    }

#pragma unroll
    for (int nt = 0; nt < 4; nt++) {
#pragma unroll
        for (int r = 0; r < 4; r++) {
            const int orow = rowbase + quad * 4 + r;
            if (orow < N) {
                const int col = nt * 16 + m;
                res[(size_t)orow * HID + col] = f2bf(acc[nt][r] + bias[col]);
            }
        }
    }
}

// ---- bucket chunk (256 thr): node hist -> pair-scan -> off/deg/dinv/ssrc
//      + fused layer-0 GEMM for the bucket's 512 rows ----
__device__ __forceinline__ void bucket_chunk(
    char* smraw, int b, const int* binned, const int* gcursor,
    int* off, int* deg, float* dinv, int* ssrc,
    const unsigned short* res, const unsigned short* wT0,
    unsigned short* hw, int N) {
    int* lh = (int*)smraw;            // [512] hist / cursor
    int* lo = lh + 512;               // [512] (only [0,256) used for pair scan)
    float* sdinv = (float*)(lo + 512);  // [512]
    const int t = threadIdx.x;
    const int e0 = b * CAP;
    const int e1 = e0 + min(gcursor[b], CAP);

    lh[t] = 0;
    lh[t + 256] = 0;
    __syncthreads();
    for (int e = e0 + t; e < e1; e += 256)
        atomicAdd(&lh[binned[e] >> 17], 1);
    __syncthreads();

    // pair scan: thread t owns local nodes 2t, 2t+1
    const int v0 = lh[2 * t], v1 = lh[2 * t + 1];
    const int pair = v0 + v1;
    lo[t] = pair;
    __syncthreads();
    for (int d = 1; d < 256; d <<= 1) {
        int xx = lo[t];
        int yy = (t >= d) ? lo[t - d] : 0;
        __syncthreads();
        lo[t] = xx + yy;
        __syncthreads();
    }
    const int pexcl = lo[t] - pair;
    const int ex0 = pexcl, ex1 = pexcl + v0;
    const int node0 = (b << BSHIFT) + 2 * t;
    const int node1 = node0 + 1;
    float dv0 = 0.0f, dv1 = 0.0f;
    if (node0 < N) {
        off[node0] = e0 + ex0;
        deg[node0] = v0;
        dv0 = rsqrtf((float)v0 + 1.0f);
        dinv[node0] = dv0;
    }
    if (node1 < N) {
        off[node1] = e0 + ex1;
        deg[node1] = v1;
        dv1 = rsqrtf((float)v1 + 1.0f);
        dinv[node1] = dv1;
    }
    sdinv[2 * t] = dv0;
    sdinv[2 * t + 1] = dv1;
    __syncthreads();
    lh[2 * t] = ex0;  // reuse as ssrc cursor
    lh[2 * t + 1] = ex1;
    __syncthreads();
    for (int e = e0 + t; e < e1; e += 256) {
        const int pk = binned[e];
        const int p = atomicAdd(&lh[pk >> 17], 1);
        ssrc[e0 + p] = pk & 0x1FFFF;
    }

    // fused layer-0 GEMM: 4 waves x 8 tiles of 16 rows = 512 rows
    const int wave = t >> 6;
    const int lane = t & 63;
    const int quad = lane >> 4;
    const int m = lane & 15;
#pragma unroll
    for (int tt = 0; tt < 8; ++tt) {
        const int rbase = wave * 128 + tt * 16;
        const int anode = (b << BSHIFT) + rbase + m;
        f32x4 acc[4];
#pragma unroll
        for (int nt = 0; nt < 4; nt++) acc[nt] = (f32x4){0.f, 0.f, 0.f, 0.f};
#pragma unroll
        for (int ks = 0; ks < HID; ks += 32) {
            bf16x8 af;
            if (anode < N) {
                af = *(const bf16x8*)&res[(size_t)anode * HID + ks + quad * 8];
            } else {
                af = (bf16x8){0, 0, 0, 0, 0, 0, 0, 0};
            }
#pragma unroll
            for (int nt = 0; nt < 4; nt++) {
                const bf16x8 bfrag = *(const bf16x8*)&wT0[(nt * 16 + m) * HID + ks + quad * 8];
                acc[nt] = __builtin_amdgcn_mfma_f32_16x16x32_bf16(af, bfrag, acc[nt], 0, 0, 0);
            }
        }
#pragma unroll
        for (int r = 0; r < 4; r++) {
            const int orow = rbase + quad * 4 + r;
            const int onode = (b << BSHIFT) + orow;
            if (onode < N) {
                const float di = sdinv[orow];
#pragma unroll
                for (int nt = 0; nt < 4; nt++) {
                    hw[(size_t)onode * HID + nt * 16 + m] = f2bf(acc[nt][r] * di);
                }
            }
        }
    }
}

// ---- agg chunk (256 thr, 32 rows): aggregate + LN (+relu+residual)
//      [+ fused next-layer GEMM when !last] ----
__device__ __forceinline__ void agg_chunk(
    char* smraw, int c, bool last,
    const int* off, const int* deg, const int* ssrc, const float* dinv,
    const unsigned short* hw_in, const float* bias, const float* gamma,
    const float* beta, unsigned short* res, float* out,
    const unsigned short* wTn, unsigned short* hw_out, int N) {
    unsigned short* lds = (unsigned short*)smraw;  // [32*64]
    const int t = threadIdx.x;
    const int lane = t & 63;
    const int wave = t >> 6;
    const int slot = lane >> 3;
    const int cgr = lane & 7;
    const int row = c * 32 + wave * 8 + slot;
    const bool rv = row < N;
    const int rowc = rv ? row : 0;

    const int p0 = rv ? off[rowc] : 0;
    const int dg = rv ? deg[rowc] : 0;
    const int p1 = p0 + dg;

    int md = dg;
    md = max(md, __shfl_xor(md, 8));
    md = max(md, __shfl_xor(md, 16));
    md = max(md, __shfl_xor(md, 32));

    float acc[8];
    {
        union { bf16x8 v; unsigned short u[8]; } sf;
        sf.v = *(const bf16x8*)&hw_in[(size_t)rowc * HID + cgr * 8];
        const float sm = rv ? 1.0f : 0.0f;
#pragma unroll
        for (int j = 0; j < 8; ++j) acc[j] = bf2f(sf.u[j]) * sm;
    }

    for (int i = 0; i < md; i += 4) {
        const int e0 = p0 + i, e1 = e0 + 1, e2 = e0 + 2, e3 = e0 + 3;
        const float m0 = (e0 < p1) ? 1.0f : 0.0f;
        const float m1 = (e1 < p1) ? 1.0f : 0.0f;
        const float m2 = (e2 < p1) ? 1.0f : 0.0f;
        const float m3 = (e3 < p1) ? 1.0f : 0.0f;
        const int s0 = ssrc[e0 < p1 ? e0 : 0];
        const int s1 = ssrc[e1 < p1 ? e1 : 0];
        const int s2 = ssrc[e2 < p1 ? e2 : 0];
        const int s3 = ssrc[e3 < p1 ? e3 : 0];
        union { bf16x8 v; unsigned short u[8]; } f0, f1, f2, f3;
        f0.v = *(const bf16x8*)&hw_in[(size_t)s0 * HID + cgr * 8];
        f1.v = *(const bf16x8*)&hw_in[(size_t)s1 * HID + cgr * 8];
        f2.v = *(const bf16x8*)&hw_in[(size_t)s2 * HID + cgr * 8];
        f3.v = *(const bf16x8*)&hw_in[(size_t)s3 * HID + cgr * 8];
#pragma unroll
        for (int j = 0; j < 8; ++j)
            acc[j] += (bf2f(f0.u[j]) * m0 + bf2f(f1.u[j]) * m1) +
                      (bf2f(f2.u[j]) * m2 + bf2f(f3.u[j]) * m3);
    }

    const float di = dinv[rowc];
    const float4 b0v = *(const float4*)&bias[cgr * 8];
    const float4 b1v = *(const float4*)&bias[cgr * 8 + 4];
    float vals[8];
    vals[0] = acc[0] * di + b0v.x;
    vals[1] = acc[1] * di + b0v.y;
    vals[2] = acc[2] * di + b0v.z;
    vals[3] = acc[3] * di + b0v.w;
    vals[4] = acc[4] * di + b1v.x;
    vals[5] = acc[5] * di + b1v.y;
    vals[6] = acc[6] * di + b1v.z;
    vals[7] = acc[7] * di + b1v.w;

    float su = ((vals[0] + vals[1]) + (vals[2] + vals[3])) +
               ((vals[4] + vals[5]) + (vals[6] + vals[7]));
    su += __shfl_xor(su, 1);
    su += __shfl_xor(su, 2);
    su += __shfl_xor(su, 4);
    const float mean = su * (1.0f / 64.0f);
    float q = 0.0f;
#pragma unroll
    for (int j = 0; j < 8; ++j) {
        const float d = vals[j] - mean;
        q += d * d;
    }
    q += __shfl_xor(q, 1);
    q += __shfl_xor(q, 2);
    q += __shfl_xor(q, 4);
    const float rstd = rsqrtf(q * (1.0f / 64.0f) + 1e-5f);

    const float4 g0v = *(const float4*)&gamma[cgr * 8];
    const float4 g1v = *(const float4*)&gamma[cgr * 8 + 4];
    const float4 t0v = *(const float4*)&beta[cgr * 8];
    const float4 t1v = *(const float4*)&beta[cgr * 8 + 4];
    float y[8];
    y[0] = (vals[0] - mean) * rstd * g0v.x + t0v.x;
    y[1] = (vals[1] - mean) * rstd * g0v.y + t0v.y;
    y[2] = (vals[2] - mean) * rstd * g0v.z + t0v.z;
    y[3] = (vals[3] - mean) * rstd * g0v.w + t0v.w;
    y[4] = (vals[4] - mean) * rstd * g1v.x + t1v.x;
    y[5] = (vals[5] - mean) * rstd * g1v.y + t1v.y;
    y[6] = (vals[6] - mean) * rstd * g1v.z + t1v.z;
    y[7] = (vals[7] - mean) * rstd * g1v.w + t1v.w;

    if (last) {
        if (rv) {
            const size_t o = (size_t)row * HID + cgr * 8;
            float4 w0v, w1v;
            w0v.x = y[0]; w0v.y = y[1]; w0v.z = y[2]; w0v.w = y[3];
            w1v.x = y[4]; w1v.y = y[5]; w1v.z = y[6]; w1v.w = y[7];
            *(float4*)&out[o] = w0v;
            *(float4*)&out[o + 4] = w1v;
        }
    } else {
        union { bf16x8 v; unsigned short u[8]; } ov;
        if (rv) {
            const size_t o = (size_t)row * HID + cgr * 8;
            union { bf16x8 v; unsigned short u[8]; } rvv;
            rvv.v = *(const bf16x8*)&res[o];
#pragma unroll
            for (int j = 0; j < 8; ++j)
                ov.u[j] = f2bf(fmaxf(y[j], 0.0f) + bf2f(rvv.u[j]));
            *(bf16x8*)&res[o] = ov.v;
        } else {
#pragma unroll
            for (int j = 0; j < 8; ++j) ov.u[j] = 0;
        }
        const int lrow = wave * 8 + slot;
        *(bf16x8*)((char*)lds + lds_swz(lrow, cgr * 16)) = ov.v;
        __syncthreads();

        if (wave < 2) {
            const int quad = lane >> 4;
            const int m = lane & 15;
            const int rowbase = c * 32 + wave * 16;
            f32x4 bacc[4];
#pragma unroll
            for (int nt = 0; nt < 4; nt++) bacc[nt] = (f32x4){0.f, 0.f, 0.f, 0.f};
#pragma unroll
            for (int ks = 0; ks < HID; ks += 32) {
                const int arow = wave * 16 + m;
                const bf16x8 afr =
                    *(const bf16x8*)((char*)lds + lds_swz(arow, (ks + quad * 8) * 2));
#pragma unroll
                for (int nt = 0; nt < 4; nt++) {
                    const bf16x8 bfrag =
                        *(const bf16x8*)&wTn[(nt * 16 + m) * HID + ks + quad * 8];
                    bacc[nt] = __builtin_amdgcn_mfma_f32_16x16x32_bf16(afr, bfrag, bacc[nt], 0, 0, 0);
                }
            }
#pragma unroll
            for (int r = 0; r < 4; r++) {
                const int orow = rowbase + quad * 4 + r;
                if (orow < N) {
                    const float dio = dinv[orow];
#pragma unroll
                    for (int nt = 0; nt < 4; nt++) {
                        hw_out[(size_t)orow * HID + nt * 16 + m] = f2bf(bacc[nt][r] * dio);
                    }
                }
            }
        }
    }
}

// ================= mega kernel (cooperative, whole pipeline) =================
__global__ __launch_bounds__(256, 4) void mega_kernel(
    const float* x, const int* src, const int* dst,
    const float* pw, const float* pb,
    const float* w0f, const float* w1f, const float* w2f,
    const float* bb0, const float* gg0, const float* be0,
    const float* bb1, const float* gg1, const float* be1,
    const float* bb2, const float* gg2, const float* be2,
    int* gcursor, int* off, int* deg, float* dinv,
    int* binned, int* ssrc,
    unsigned short* res, unsigned short* hwA, unsigned short* hwB,
    unsigned short* pwT, unsigned short* wT, float* out,
    int N, int E, int PB, int PJ, int NBUK, int AG) {
    __shared__ __align__(16) char smraw[SMBYTES];
    cg::grid_group grid = cg::this_grid();
    const int nb = gridDim.x;

    // P0: prep (zero cursors + weight transposes)
    for (int c = blockIdx.x; c < 5; c += nb)
        prep_chunk(c, gcursor, pw, w0f, w1f, w2f, pwT, wT);
    grid.sync();

    // P1: partition into fixed bucket regions ∥ input projection
    for (int c = blockIdx.x; c < PB + PJ; c += nb) {
        if (c < PB) partition_chunk(smraw, c, src, dst, gcursor, binned, E);
        else proj_chunk(c - PB, x, pwT, pb, res, N);
        __syncthreads();
    }
    grid.sync();

    // P2: bucket CSR finalize + fused layer-0 GEMM
    for (int c = blockIdx.x; c < NBUK; c += nb) {
        bucket_chunk(smraw, c, binned, gcursor, off, deg, dinv, ssrc, res, wT, hwA, N);
        __syncthreads();
    }
    grid.sync();

    // P3: layer 0 (agg + LN + relu + residual + fused gemm1)
    for (int c = blockIdx.x; c < AG; c += nb) {
        agg_chunk(smraw, c, false, off, deg, ssrc, dinv, hwA, bb0, gg0, be0,
                  res, nullptr, wT + (size_t)1 * HID * HID, hwB, N);
        __syncthreads();
    }
    grid.sync();

    // P4: layer 1 (fused gemm2)
    for (int c = blockIdx.x; c < AG; c += nb) {
        agg_chunk(smraw, c, false, off, deg, ssrc, dinv, hwB, bb1, gg1, be1,
                  res, nullptr, wT + (size_t)2 * HID * HID, hwA, N);
        __syncthreads();
    }
    grid.sync();

    // P5: layer 2 (last -> fp32 out)
    for (int c = blockIdx.x; c < AG; c += nb) {
        agg_chunk(smraw, c, true, off, deg, ssrc, dinv, hwA, bb2, gg2, be2,
                  nullptr, out, nullptr, nullptr, N);
    }
}

// ================= fallback wrappers (R7-equivalent sequence) ===============
__global__ __launch_bounds__(256, 4) void prep_wrap(
    int* gcursor, const float* pw, const float* w0f, const float* w1f,
    const float* w2f, unsigned short* pwT, unsigned short* wT) {
    prep_chunk(blockIdx.x, gcursor, pw, w0f, w1f, w2f, pwT, wT);
}

__global__ __launch_bounds__(256, 4) void partition_proj_wrap(
    const int* src, const int* dst, int* gcursor, int* binned, int E, int PB,
    const float* x, const unsigned short* pwT, const float* pb,
    unsigned short* res, int N) {
    __shared__ __align__(16) char smraw[SMBYTES];
    if ((int)blockIdx.x < PB) partition_chunk(smraw, blockIdx.x, src, dst, gcursor, binned, E);
    else proj_chunk(blockIdx.x - PB, x, pwT, pb, res, N);
}

__global__ __launch_bounds__(256, 4) void bucket_wrap(
    const int* binned, const int* gcursor, int* off, int* deg, float* dinv,
    int* ssrc, const unsigned short* res, const unsigned short* wT0,
    unsigned short* hw, int N) {
    __shared__ __align__(16) char smraw[6144];
    bucket_chunk(smraw, blockIdx.x, binned, gcursor, off, deg, dinv, ssrc, res,
                 wT0, hw, N);
}

template <bool LAST>
__global__ __launch_bounds__(256, 4) void agg_wrap(
    const int* off, const int* deg, const int* ssrc, const float* dinv,
    const unsigned short* hw_in, const float* bias, const float* gamma,
    const float* beta, unsigned short* res, float* out,
    const unsigned short* wTn, unsigned short* hw_out, int N) {
    __shared__ __align__(16) char smraw[4096];
    agg_chunk(smraw, blockIdx.x, LAST, off, deg, ssrc, dinv, hw_in, bias, gamma,
              beta, res, out, wTn, hw_out, N);
}

extern "C" void kernel_launch(void* const* d_in, const int* in_sizes, int n_in,
                              void* d_out, int out_size, void* d_ws, size_t ws_size,
                              hipStream_t stream) {
    const float* x      = (const float*)d_in[0];
    const int*   ei     = (const int*)d_in[1];
    const float* proj_w = (const float*)d_in[2];
    const float* proj_b = (const float*)d_in[3];
    const float* w0p  = (const float*)d_in[4];
    const float* b0p  = (const float*)d_in[5];
    const float* g0p  = (const float*)d_in[6];
    const float* be0p = (const float*)d_in[7];
    const float* w1p  = (const float*)d_in[8];
    const float* b1p  = (const float*)d_in[9];
    const float* g1p  = (const float*)d_in[10];
    const float* be1p = (const float*)d_in[11];
    const float* w2p  = (const float*)d_in[12];
    const float* b2p  = (const float*)d_in[13];
    const float* g2p  = (const float*)d_in[14];
    const float* be2p = (const float*)d_in[15];

    const int N = in_sizes[0] / IN_CH;
    const int E = in_sizes[1] / 2;
    const int* src = ei;
    const int* dst = ei + E;
    const int NBUK = (N + (1 << BSHIFT) - 1) >> BSHIFT;
    const int PB = (E + EPB - 1) / EPB;
    const int PJ = (N + 63) / 64;
    const int AG = (N + 31) / 32;

    char* wsb = (char*)d_ws;
    size_t o2 = 0;
    auto alloc = [&](size_t bytes) {
        void* p = wsb + o2;
        o2 = (o2 + bytes + 255) & ~(size_t)255;
        return p;
    };
    int*   gcursor = (int*)alloc((size_t)NBUK_MAX * 4);
    int*   off     = (int*)alloc((size_t)N * 4);
    int*   deg     = (int*)alloc((size_t)N * 4);
    float* dinv    = (float*)alloc((size_t)N * 4);
    int*   binned  = (int*)alloc((size_t)NBUK_MAX * CAP * 4);
    int*   ssrc    = (int*)alloc((size_t)NBUK_MAX * CAP * 4);
    unsigned short* res = (unsigned short*)alloc((size_t)N * HID * 2);
    unsigned short* hwA = (unsigned short*)alloc((size_t)N * HID * 2);
    unsigned short* hwB = (unsigned short*)alloc((size_t)N * HID * 2);
    unsigned short* pwT = (unsigned short*)alloc((size_t)HID * IN_CH * 2);
    unsigned short* wT  = (unsigned short*)alloc((size_t)3 * HID * HID * 2);
    float* outp = (float*)d_out;

    // cooperative grid size: blocks/CU from occupancy query, 256 CUs (MI355X)
    static int s_grid = 0;
    if (s_grid == 0) {
        int bpc = 0;
        if (hipOccupancyMaxActiveBlocksPerMultiprocessor(&bpc, mega_kernel, 256, 0)
                != hipSuccess || bpc < 1) bpc = 4;
        if (bpc > 8) bpc = 8;
        s_grid = bpc * 256;
    }

    int Nv = N, Ev = E, PBv = PB, PJv = PJ, NBUKv = NBUK, AGv = AG;
    void* kargs[] = {
        (void*)&x, (void*)&src, (void*)&dst, (void*)&proj_w, (void*)&proj_b,
        (void*)&w0p, (void*)&w1p, (void*)&w2p,
        (void*)&b0p, (void*)&g0p, (void*)&be0p,
        (void*)&b1p, (void*)&g1p, (void*)&be1p,
        (void*)&b2p, (void*)&g2p, (void*)&be2p,
        (void*)&gcursor, (void*)&off, (void*)&deg, (void*)&dinv,
        (void*)&binned, (void*)&ssrc,
        (void*)&res, (void*)&hwA, (void*)&hwB, (void*)&pwT, (void*)&wT,
        (void*)&outp,
        (void*)&Nv, (void*)&Ev, (void*)&PBv, (void*)&PJv, (void*)&NBUKv,
        (void*)&AGv};

    hipError_t ce = hipLaunchCooperativeKernel(
        (const void*)mega_kernel, dim3(s_grid), dim3(256), kargs, 0, stream);

    if (ce != hipSuccess) {
        // fallback: R7-equivalent 6-dispatch sequence (same chunk bodies)
        prep_wrap<<<5, 256, 0, stream>>>(gcursor, proj_w, w0p, w1p, w2p, pwT, wT);
        partition_proj_wrap<<<PB + PJ, 256, 0, stream>>>(
            src, dst, gcursor, binned, E, PB, x, pwT, proj_b, res, N);
        bucket_wrap<<<NBUK, 256, 0, stream>>>(binned, gcursor, off, deg, dinv,
                                              ssrc, res, wT, hwA, N);
        agg_wrap<false><<<AG, 256, 0, stream>>>(
            off, deg, ssrc, dinv, hwA, b0p, g0p, be0p, res, nullptr,
            wT + (size_t)1 * HID * HID, hwB, N);
        agg_wrap<false><<<AG, 256, 0, stream>>>(
            off, deg, ssrc, dinv, hwB, b1p, g1p, be1p, res, nullptr,
            wT + (size_t)2 * HID * HID, hwA, N);
        agg_wrap<true><<<AG, 256, 0, stream>>>(
            off, deg, ssrc, dinv, hwA, b2p, g2p, be2p, nullptr, outp,
            nullptr, nullptr, N);
    }
}

// Round 9
// 256.291 us; speedup vs baseline: 2.4272x; 2.4272x over previous
//
#include <hip/hip_runtime.h>

#define HID 64
#define IN_CH 128

#define BSHIFT 9          // 512 nodes per bucket
#define NBUK_MAX 256      // supports N up to 131072 (src packed in 17 bits)
#define CAP 16384         // fixed edge capacity per bucket region (~3x headroom)
#define EPB 2048          // edges per partition block

typedef __attribute__((ext_vector_type(8))) short bf16x8;
typedef __attribute__((ext_vector_type(4))) float f32x4;

// ---------- bf16 helpers (RNE) ----------
__device__ __forceinline__ float bf2f(unsigned short u) {
    return __uint_as_float((unsigned)u << 16);
}
__device__ __forceinline__ unsigned short f2bf(float f) {
    unsigned u = __float_as_uint(f);
    unsigned r = u + 0x7FFFu + ((u >> 16) & 1u);
    return (unsigned short)(r >> 16);
}

// swizzled LDS byte offset for a [rows][64] bf16 tile (row stride 128B).
// XOR of (row&7)<<4 spreads the 16B column slots across banks (T2 pattern).
__device__ __forceinline__ int lds_swz(int row, int byte_col) {
    return row * 128 + (byte_col ^ ((row & 7) << 4));
}

// ============ prep: zero gcursor + weight transposes ============
__global__ __launch_bounds__(256) void prep_kernel(
    int* __restrict__ gcursor,
    const float* __restrict__ pw, const float* __restrict__ w0,
    const float* __restrict__ w1, const float* __restrict__ w2,
    unsigned short* __restrict__ pwT, unsigned short* __restrict__ wT) {
    const int id = blockIdx.x;
    const int t = threadIdx.x;
    if (id == 0) {
        if (t < NBUK_MAX) gcursor[t] = 0;
    } else if (id == 1) {
        for (int i = t; i < IN_CH * HID; i += 256) {
            const int k = i >> 6, n = i & 63;
            pwT[n * IN_CH + k] = f2bf(pw[i]);
        }
    } else {
        const int wi = id - 2;  // 0..2
        const float* w = (wi == 0) ? w0 : (wi == 1) ? w1 : w2;
        unsigned short* o = wT + (size_t)wi * HID * HID;
        for (int i = t; i < HID * HID; i += 256) {
            const int k = i >> 6, n = i & 63;
            o[n * HID + k] = f2bf(w[i]);
        }
    }
}

// ============ merged: partition (blocks [0,PB)) + proj (blocks [PB,PB+PJ)) ==
// partition: LDS counting-sort by bucket, write packed src|(dlocal<<17) into
//   the bucket's FIXED region [b*CAP, b*CAP+CAP) at atomically-claimed ranks.
//   (no bucket histogram/scan pass needed at all)
// proj: res = bf16(x@pwT + pb), 64 rows/block, 4 waves x 16 rows (independent
//   work co-scheduled with partition to fill the GPU)
__global__ __launch_bounds__(256) void partition_proj_kernel(
    const int* __restrict__ src, const int* __restrict__ dst,
    int* __restrict__ gcursor, int* __restrict__ binned, int E, int PB,
    const float* __restrict__ A, const unsigned short* __restrict__ pwT,
    const float* __restrict__ bias, unsigned short* __restrict__ res, int N) {
    const int t = threadIdx.x;
    if (blockIdx.x < PB) {
        // ---------------- partition ----------------
        __shared__ int lh[NBUK_MAX];     // per-bucket count (atomic rank)
        __shared__ int loff[NBUK_MAX];   // exclusive scan of counts
        __shared__ int gbase[NBUK_MAX];  // global base per bucket
        __shared__ int2 stage[EPB];

        const int base = blockIdx.x * EPB;
        const int count = min(EPB, E - base);

        for (int i = t; i < NBUK_MAX; i += 256) lh[i] = 0;
        __syncthreads();

        constexpr int EPT = EPB / 256;
        int myS[EPT], myD[EPT], myR[EPT];
#pragma unroll
        for (int j = 0; j < EPT; ++j) {
            const int e = base + j * 256 + t;
            if (e < E) {
                myS[j] = src[e];
                myD[j] = dst[e];
                myR[j] = atomicAdd(&lh[myD[j] >> BSHIFT], 1);
            }
        }
        __syncthreads();

        const int v = lh[t];
        loff[t] = v;
        __syncthreads();
        for (int d = 1; d < 256; d <<= 1) {
            int x = loff[t];
            int y = (t >= d) ? loff[t - d] : 0;
            __syncthreads();
            loff[t] = x + y;
            __syncthreads();
        }
        const int excl = loff[t] - v;
        __syncthreads();
        loff[t] = excl;
        if (v > 0) gbase[t] = t * CAP + atomicAdd(&gcursor[t], v);
        __syncthreads();

#pragma unroll
        for (int j = 0; j < EPT; ++j) {
            const int e = base + j * 256 + t;
            if (e < E) {
                const int b = myD[j] >> BSHIFT;
                stage[loff[b] + myR[j]] = make_int2(myS[j], myD[j]);
            }
        }
        __syncthreads();

        for (int i = t; i < count; i += 256) {
            const int2 ed = stage[i];
            const int b = ed.y >> BSHIFT;
            const int pos = gbase[b] + (i - loff[b]);
            if (pos - b * CAP < CAP) {  // overflow guard (CAP >> expected load)
                const int pk = ed.x | ((ed.y & ((1 << BSHIFT) - 1)) << 17);
                binned[pos] = pk;
            }
        }
        return;
    }
    // ---------------- projection: res = bf16(x@pwT + pb) ----------------
    const int wave = t >> 6;
    const int lane = t & 63;
    const int quad = lane >> 4;
    const int m = lane & 15;
    const int rowbase = (blockIdx.x - PB) * 64 + wave * 16;
    const int row = rowbase + m;

    f32x4 acc[4];
#pragma unroll
    for (int nt = 0; nt < 4; nt++) acc[nt] = (f32x4){0.f, 0.f, 0.f, 0.f};

#pragma unroll
    for (int ks = 0; ks < IN_CH; ks += 32) {
        union { bf16x8 v; unsigned short u[8]; } af;
        if (row < N) {
            const float4 a0 = *(const float4*)&A[(size_t)row * IN_CH + ks + quad * 8];
            const float4 a1 = *(const float4*)&A[(size_t)row * IN_CH + ks + quad * 8 + 4];
            af.u[0] = f2bf(a0.x); af.u[1] = f2bf(a0.y);
            af.u[2] = f2bf(a0.z); af.u[3] = f2bf(a0.w);
            af.u[4] = f2bf(a1.x); af.u[5] = f2bf(a1.y);
            af.u[6] = f2bf(a1.z); af.u[7] = f2bf(a1.w);
        } else {
#pragma unroll
            for (int j = 0; j < 8; j++) af.u[j] = 0;
        }
#pragma unroll
        for (int nt = 0; nt < 4; nt++) {
            const bf16x8 bfrag = *(const bf16x8*)&pwT[(nt * 16 + m) * IN_CH + ks + quad * 8];
            acc[nt] = __builtin_amdgcn_mfma_f32_16x16x32_bf16(af.v, bfrag, acc[nt], 0, 0, 0);
        }
    }

#pragma unroll
    for (int nt = 0; nt < 4; nt++) {
#pragma unroll
        for (int r = 0; r < 4; r++) {
            const int orow = rowbase + quad * 4 + r;
            if (orow < N) {
                const int col = nt * 16 + m;
                res[(size_t)orow * HID + col] = f2bf(acc[nt][r] + bias[col]);
            }
        }
    }
}

// ---- one block per bucket: node hist -> scan -> off/deg/dinv/ssrc
//      + fused layer-0 GEMM: hw0 = bf16((res@W0) * dinv) for own 512 rows ----
__global__ __launch_bounds__(512) void bucket_csr_gemm_kernel(
    const int* __restrict__ binned, const int* __restrict__ gcursor,
    int* __restrict__ off, int* __restrict__ deg, float* __restrict__ dinv,
    int* __restrict__ ssrc,
    const unsigned short* __restrict__ res, const unsigned short* __restrict__ wT0,
    unsigned short* __restrict__ hw, int N) {
    __shared__ int lh[512];
    __shared__ int lo[512];
    __shared__ float sdinv[512];
    const int b = blockIdx.x;
    const int t = threadIdx.x;
    const int e0 = b * CAP;
    const int e1 = e0 + min(gcursor[b], CAP);

    lh[t] = 0;
    __syncthreads();
    for (int e = e0 + t; e < e1; e += 512)
        atomicAdd(&lh[binned[e] >> 17], 1);
    __syncthreads();

    const int v = lh[t];
    lo[t] = v;
    __syncthreads();
    for (int d = 1; d < 512; d <<= 1) {
        int x = lo[t];
        int y = (t >= d) ? lo[t - d] : 0;
        __syncthreads();
        lo[t] = x + y;
        __syncthreads();
    }
    const int excl = lo[t] - v;
    const int node = (b << BSHIFT) + t;
    const bool valid = node < N;
    float dv = 0.0f;
    if (valid) {
        off[node] = e0 + excl;
        deg[node] = v;
        dv = rsqrtf((float)v + 1.0f);  // +1 self-loop
        dinv[node] = dv;
    }
    sdinv[t] = dv;
    __syncthreads();
    lh[t] = excl;  // reuse as ssrc cursor
    __syncthreads();
    for (int e = e0 + t; e < e1; e += 512) {
        const int pk = binned[e];
        const int p = atomicAdd(&lh[pk >> 17], 1);
        ssrc[e0 + p] = pk & 0x1FFFF;  // global src index (17 bits)
    }

    // ---- fused layer-0 GEMM for this bucket's 512 rows ----
    // wave w handles rows [64w, 64w+64) as 4 x 16-row MFMA tiles
    const int wave = t >> 6;
    const int lane = t & 63;
    const int quad = lane >> 4;
    const int m = lane & 15;
#pragma unroll
    for (int tt = 0; tt < 4; ++tt) {
        const int rbase = wave * 64 + tt * 16;
        const int anode = (b << BSHIFT) + rbase + m;
        f32x4 acc[4];
#pragma unroll
        for (int nt = 0; nt < 4; nt++) acc[nt] = (f32x4){0.f, 0.f, 0.f, 0.f};
#pragma unroll
        for (int ks = 0; ks < HID; ks += 32) {
            bf16x8 af;
            if (anode < N) {
                af = *(const bf16x8*)&res[(size_t)anode * HID + ks + quad * 8];
            } else {
                af = (bf16x8){0, 0, 0, 0, 0, 0, 0, 0};
            }
#pragma unroll
            for (int nt = 0; nt < 4; nt++) {
                const bf16x8 bfrag = *(const bf16x8*)&wT0[(nt * 16 + m) * HID + ks + quad * 8];
                acc[nt] = __builtin_amdgcn_mfma_f32_16x16x32_bf16(af, bfrag, acc[nt], 0, 0, 0);
            }
        }
#pragma unroll
        for (int r = 0; r < 4; r++) {
            const int orow = rbase + quad * 4 + r;
            const int onode = (b << BSHIFT) + orow;
            if (onode < N) {
                const float di = sdinv[orow];
#pragma unroll
                for (int nt = 0; nt < 4; nt++) {
                    hw[(size_t)onode * HID + nt * 16 + m] = f2bf(acc[nt][r] * di);
                }
            }
        }
    }
}

// ============ fused aggregate + LayerNorm (+relu+residual) [+ next GEMM] ==
// hw_in is prescaled by dinv. out_row = di*(hw[row] + sum_edges hw[s]) + bias.
// Wave layout: 8 rows/wave; slot=lane>>3 row, cg=lane&7 channels cg*8..+7.
// Row edge range: [off[row], off[row]+deg[row]) in the padded ssrc space.
// Edge loop 4-deep (ILP-8 regressed in R5); masked tail loads hit clamped
// ssrc line -> L1, nearly free.
// !LAST: res(bf16) += relu(LN(...)) in place, then fused next-layer GEMM:
//        hw_out = bf16((res_new @ wTn) * dinv) via swizzled LDS bounce.
// LAST:  out(fp32) = LN(...).
template <bool LAST>
__global__ __launch_bounds__(256) void agg_ln_gemm_kernel(
    const int* __restrict__ off, const int* __restrict__ deg,
    const int* __restrict__ ssrc,
    const float* __restrict__ dinv, const unsigned short* __restrict__ hw_in,
    const float* __restrict__ bias, const float* __restrict__ g,
    const float* __restrict__ beta, unsigned short* __restrict__ res,
    float* __restrict__ out, const unsigned short* __restrict__ wTn,
    unsigned short* __restrict__ hw_out, int N) {
    __shared__ unsigned short lds[32 * 64];  // 4 KB, swizzled (unused if LAST)
    const int lane = threadIdx.x & 63;
    const int wave = threadIdx.x >> 6;
    const int slot = lane >> 3;  // row slot 0..7
    const int cg = lane & 7;     // channel group: channels cg*8..cg*8+7
    const int row = blockIdx.x * 32 + wave * 8 + slot;
    const bool rv = row < N;
    const int rowc = rv ? row : 0;  // clamped for safe loads

    const int p0 = rv ? off[rowc] : 0;
    const int dg = rv ? deg[rowc] : 0;
    const int p1 = p0 + dg;

    // wave-max degree (differs only across the 8 slots)
    int md = dg;
    md = max(md, __shfl_xor(md, 8));
    md = max(md, __shfl_xor(md, 16));
    md = max(md, __shfl_xor(md, 32));

    float acc[8];
    {
        // self-loop row (prescaled) — one slot per row, no redundancy
        union { bf16x8 v; unsigned short u[8]; } sf;
        sf.v = *(const bf16x8*)&hw_in[(size_t)rowc * HID + cg * 8];
        const float sm = rv ? 1.0f : 0.0f;
#pragma unroll
        for (int j = 0; j < 8; ++j) acc[j] = bf2f(sf.u[j]) * sm;
    }

    // edge loop: 4 gathers in flight (masked; clamped index p0 stays within
    // this row's padded region; for dg==0 rows all masks are 0)
    for (int i = 0; i < md; i += 4) {
        const int e0 = p0 + i, e1 = e0 + 1, e2 = e0 + 2, e3 = e0 + 3;
        const float m0 = (e0 < p1) ? 1.0f : 0.0f;
        const float m1 = (e1 < p1) ? 1.0f : 0.0f;
        const float m2 = (e2 < p1) ? 1.0f : 0.0f;
        const float m3 = (e3 < p1) ? 1.0f : 0.0f;
        const int s0 = ssrc[e0 < p1 ? e0 : 0];
        const int s1 = ssrc[e1 < p1 ? e1 : 0];
        const int s2 = ssrc[e2 < p1 ? e2 : 0];
        const int s3 = ssrc[e3 < p1 ? e3 : 0];
        union { bf16x8 v; unsigned short u[8]; } f0, f1, f2, f3;
        f0.v = *(const bf16x8*)&hw_in[(size_t)s0 * HID + cg * 8];
        f1.v = *(const bf16x8*)&hw_in[(size_t)s1 * HID + cg * 8];
        f2.v = *(const bf16x8*)&hw_in[(size_t)s2 * HID + cg * 8];
        f3.v = *(const bf16x8*)&hw_in[(size_t)s3 * HID + cg * 8];
#pragma unroll
        for (int j = 0; j < 8; ++j)
            acc[j] += (bf2f(f0.u[j]) * m0 + bf2f(f1.u[j]) * m1) +
                      (bf2f(f2.u[j]) * m2 + bf2f(f3.u[j]) * m3);
    }

    const float di = dinv[rowc];
    const float4 b0 = *(const float4*)&bias[cg * 8];
    const float4 b1 = *(const float4*)&bias[cg * 8 + 4];
    float vals[8];
    vals[0] = acc[0] * di + b0.x;
    vals[1] = acc[1] * di + b0.y;
    vals[2] = acc[2] * di + b0.z;
    vals[3] = acc[3] * di + b0.w;
    vals[4] = acc[4] * di + b1.x;
    vals[5] = acc[5] * di + b1.y;
    vals[6] = acc[6] * di + b1.z;
    vals[7] = acc[7] * di + b1.w;

    // LayerNorm over 64 channels: in-lane sum of 8 + butterfly over octet
    float su = ((vals[0] + vals[1]) + (vals[2] + vals[3])) +
               ((vals[4] + vals[5]) + (vals[6] + vals[7]));
    su += __shfl_xor(su, 1);
    su += __shfl_xor(su, 2);
    su += __shfl_xor(su, 4);
    const float mean = su * (1.0f / 64.0f);
    float q = 0.0f;
#pragma unroll
    for (int j = 0; j < 8; ++j) {
        const float d = vals[j] - mean;
        q += d * d;
    }
    q += __shfl_xor(q, 1);
    q += __shfl_xor(q, 2);
    q += __shfl_xor(q, 4);
    const float rstd = rsqrtf(q * (1.0f / 64.0f) + 1e-5f);

    const float4 g0 = *(const float4*)&g[cg * 8];
    const float4 g1 = *(const float4*)&g[cg * 8 + 4];
    const float4 t0 = *(const float4*)&beta[cg * 8];
    const float4 t1 = *(const float4*)&beta[cg * 8 + 4];
    float y[8];
    y[0] = (vals[0] - mean) * rstd * g0.x + t0.x;
    y[1] = (vals[1] - mean) * rstd * g0.y + t0.y;
    y[2] = (vals[2] - mean) * rstd * g0.z + t0.z;
    y[3] = (vals[3] - mean) * rstd * g0.w + t0.w;
    y[4] = (vals[4] - mean) * rstd * g1.x + t1.x;
    y[5] = (vals[5] - mean) * rstd * g1.y + t1.y;
    y[6] = (vals[6] - mean) * rstd * g1.z + t1.z;
    y[7] = (vals[7] - mean) * rstd * g1.w + t1.w;

    if (LAST) {
        if (rv) {
            const size_t o = (size_t)row * HID + cg * 8;
            float4 w0, w1;
            w0.x = y[0]; w0.y = y[1]; w0.z = y[2]; w0.w = y[3];
            w1.x = y[4]; w1.y = y[5]; w1.z = y[6]; w1.w = y[7];
            *(float4*)&out[o] = w0;
            *(float4*)&out[o + 4] = w1;
        }
    } else {
        union { bf16x8 v; unsigned short u[8]; } ov;
        if (rv) {
            const size_t o = (size_t)row * HID + cg * 8;
            union { bf16x8 v; unsigned short u[8]; } rvv;
            rvv.v = *(const bf16x8*)&res[o];
#pragma unroll
            for (int j = 0; j < 8; ++j)
                ov.u[j] = f2bf(fmaxf(y[j], 0.0f) + bf2f(rvv.u[j]));
            *(bf16x8*)&res[o] = ov.v;  // in-place: own row only
        } else {
#pragma unroll
            for (int j = 0; j < 8; ++j) ov.u[j] = 0;
        }
        // stage new res row in LDS for the fused next-layer GEMM
        const int lrow = wave * 8 + slot;
        *(bf16x8*)((char*)lds + lds_swz(lrow, cg * 16)) = ov.v;
        __syncthreads();

        // waves 0,1: one 16-row MFMA tile each over the staged 32 rows
        if (wave < 2) {
            const int quad = lane >> 4;
            const int m = lane & 15;
            const int rowbase = blockIdx.x * 32 + wave * 16;
            f32x4 bacc[4];
#pragma unroll
            for (int nt = 0; nt < 4; nt++) bacc[nt] = (f32x4){0.f, 0.f, 0.f, 0.f};
#pragma unroll
            for (int ks = 0; ks < HID; ks += 32) {
                const int arow = wave * 16 + m;
                const bf16x8 afr =
                    *(const bf16x8*)((char*)lds + lds_swz(arow, (ks + quad * 8) * 2));
#pragma unroll
                for (int nt = 0; nt < 4; nt++) {
                    const bf16x8 bfrag =
                        *(const bf16x8*)&wTn[(nt * 16 + m) * HID + ks + quad * 8];
                    bacc[nt] = __builtin_amdgcn_mfma_f32_16x16x32_bf16(afr, bfrag, bacc[nt], 0, 0, 0);
                }
            }
#pragma unroll
            for (int r = 0; r < 4; r++) {
                const int orow = rowbase + quad * 4 + r;
                if (orow < N) {
                    const float dio = dinv[orow];
#pragma unroll
                    for (int nt = 0; nt < 4; nt++) {
                        hw_out[(size_t)orow * HID + nt * 16 + m] = f2bf(bacc[nt][r] * dio);
                    }
                }
            }
        }
    }
}

extern "C" void kernel_launch(void* const* d_in, const int* in_sizes, int n_in,
                              void* d_out, int out_size, void* d_ws, size_t ws_size,
                              hipStream_t stream) {
    const float* x      = (const float*)d_in[0];
    const int*   ei     = (const int*)d_in[1];
    const float* proj_w = (const float*)d_in[2];
    const float* proj_b = (const float*)d_in[3];
    const float* w[3]  = {(const float*)d_in[4], (const float*)d_in[8],  (const float*)d_in[12]};
    const float* b[3]  = {(const float*)d_in[5], (const float*)d_in[9],  (const float*)d_in[13]};
    const float* g[3]  = {(const float*)d_in[6], (const float*)d_in[10], (const float*)d_in[14]};
    const float* be[3] = {(const float*)d_in[7], (const float*)d_in[11], (const float*)d_in[15]};

    const int N = in_sizes[0] / IN_CH;
    const int E = in_sizes[1] / 2;
    const int* src = ei;
    const int* dst = ei + E;
    const int nbuk = (N + (1 << BSHIFT) - 1) >> BSHIFT;
    const int PB = (E + EPB - 1) / EPB;
    const int PJ = (N + 63) / 64;

    char* wsb = (char*)d_ws;
    size_t o2 = 0;
    auto alloc = [&](size_t bytes) {
        void* p = wsb + o2;
        o2 = (o2 + bytes + 255) & ~(size_t)255;
        return p;
    };
    int*   gcursor = (int*)alloc((size_t)NBUK_MAX * 4);
    int*   off     = (int*)alloc((size_t)N * 4);
    int*   deg     = (int*)alloc((size_t)N * 4);
    float* dinv    = (float*)alloc((size_t)N * 4);
    int*   binned  = (int*)alloc((size_t)NBUK_MAX * CAP * 4);  // padded regions
    int*   ssrc    = (int*)alloc((size_t)NBUK_MAX * CAP * 4);  // padded regions
    unsigned short* res = (unsigned short*)alloc((size_t)N * HID * 2);  // residual bf16
    unsigned short* hwA = (unsigned short*)alloc((size_t)N * HID * 2);  // ping
    unsigned short* hwB = (unsigned short*)alloc((size_t)N * HID * 2);  // pong
    unsigned short* pwT = (unsigned short*)alloc((size_t)HID * IN_CH * 2);
    unsigned short* wT  = (unsigned short*)alloc((size_t)3 * HID * HID * 2);

    // ---- prep: zero cursors + weight transposes (1 small dispatch) ----
    prep_kernel<<<5, 256, 0, stream>>>(gcursor, proj_w, w[0], w[1], w[2], pwT, wT);

    // ---- partition into fixed-capacity bucket regions ∥ input projection ----
    partition_proj_kernel<<<PB + PJ, 256, 0, stream>>>(
        src, dst, gcursor, binned, E, PB, x, pwT, proj_b, res, N);

    // ---- CSR finalize (off/deg/dinv/ssrc) + fused layer-0 GEMM ----
    bucket_csr_gemm_kernel<<<nbuk, 512, 0, stream>>>(binned, gcursor, off, deg,
                                                     dinv, ssrc, res, wT, hwA, N);

    // ---- 3 GCN layers; gemm_{l+1} fused into agg_l; hw double-buffered ----
    agg_ln_gemm_kernel<false><<<(N + 31) / 32, 256, 0, stream>>>(
        off, deg, ssrc, dinv, hwA, b[0], g[0], be[0], res, nullptr,
        wT + (size_t)1 * HID * HID, hwB, N);
    agg_ln_gemm_kernel<false><<<(N + 31) / 32, 256, 0, stream>>>(
        off, deg, ssrc, dinv, hwB, b[1], g[1], be[1], res, nullptr,
        wT + (size_t)2 * HID * HID, hwA, N);
    agg_ln_gemm_kernel<true><<<(N + 31) / 32, 256, 0, stream>>>(
        off, deg, ssrc, dinv, hwA, b[2], g[2], be[2], nullptr, (float*)d_out,
        nullptr, nullptr, N);
}